// Round 6
// baseline (577.108 us; speedup 1.0000x reference)
//
#include <hip/hip_runtime.h>
#include <math.h>

#define BT      4096
#define T_SEQ   2048
#define E_DIM   1024
#define V_DIM   2048
#define DK      128
#define DV      256

typedef unsigned short ushort_t;
typedef __attribute__((ext_vector_type(8)))  short bf16x8;
typedef __attribute__((ext_vector_type(4)))  unsigned short u16x4;
typedef __attribute__((ext_vector_type(16))) float f32x16;

__device__ __forceinline__ void decay_params(int h, float& ld, float& gamma) {
    const float s0 = -3.4657359027997265f;  // ln(1/32)
    const float e0 = -6.2383246250395092f;  // ln(1/512)
    float lin = s0 + (e0 - s0) * ((float)h * (1.0f / 7.0f));
    gamma = 1.0f - expf(lin);
    ld = logf(gamma);
}

__device__ __forceinline__ short f2bf(float f) {
    unsigned u = __float_as_uint(f);
    unsigned r = (u + 0x7fffu + ((u >> 16) & 1u)) >> 16;
    return (short)r;
}
__device__ __forceinline__ float bf2f(ushort_t u) {
    return __uint_as_float((unsigned)u << 16);
}

__device__ __forceinline__ void async_copy16(void* lds, const void* g) {
    __builtin_amdgcn_global_load_lds(
        (const __attribute__((address_space(1))) unsigned int*)g,
        (__attribute__((address_space(3))) unsigned int*)lds, 16, 0, 0);
}

// ---------------------------------------------------------------------------
// fp32 -> bf16 elementwise
// ---------------------------------------------------------------------------
__global__ __launch_bounds__(256)
void f32_to_bf16_kernel(const float* __restrict__ in, ushort_t* __restrict__ out)
{
    int i = (blockIdx.x * 256 + threadIdx.x) * 8;
    float4 a = *(const float4*)&in[i];
    float4 b = *(const float4*)&in[i + 4];
    bf16x8 o;
    o[0] = f2bf(a.x); o[1] = f2bf(a.y); o[2] = f2bf(a.z); o[3] = f2bf(a.w);
    o[4] = f2bf(b.x); o[5] = f2bf(b.y); o[6] = f2bf(b.z); o[7] = f2bf(b.w);
    *(bf16x8*)&out[i] = o;
}

// ---------------------------------------------------------------------------
// W[K][N] fp32 -> Wt[N][K] bf16
// ---------------------------------------------------------------------------
__global__ __launch_bounds__(256)
void transpose_w_kernel(const float* __restrict__ W, ushort_t* __restrict__ Wt,
                        int K, int N)
{
    __shared__ float tile[32][33];
    const int k0 = blockIdx.y * 32, n0 = blockIdx.x * 32;
    const int t = threadIdx.x;
    const int r = t >> 3, c = (t & 7) * 4;
    float4 v = *(const float4*)&W[(size_t)(k0 + r) * N + n0 + c];
    tile[r][c] = v.x; tile[r][c + 1] = v.y; tile[r][c + 2] = v.z; tile[r][c + 3] = v.w;
    __syncthreads();
    u16x4 o;
    o[0] = (ushort_t)f2bf(tile[c][r]);
    o[1] = (ushort_t)f2bf(tile[c + 1][r]);
    o[2] = (ushort_t)f2bf(tile[c + 2][r]);
    o[3] = (ushort_t)f2bf(tile[c + 3][r]);
    *(u16x4*)&Wt[(size_t)(n0 + r) * K + k0 + c] = o;
}

// ---------------------------------------------------------------------------
// bf16 MFMA GEMM, 128x128 tile, BK=32, 4 waves of 2x2 mfma_32x32x16.
// EPI 1: bf16 out = silu(acc + bias[col]) * bf2f(extra[row][col])
// EPI 2: bf16 out in vt layout [b*8+h][v][t] (row=v-feature, col=token),
//        bias indexed by row.
// ---------------------------------------------------------------------------
template<int EPI>
__global__ __launch_bounds__(256)
void gemm_bf16(const ushort_t* __restrict__ A, int lda,
               const ushort_t* __restrict__ Bt, int ldb,
               const float* __restrict__ bias,
               void* __restrict__ Cv, int ldc,
               const void* __restrict__ extra, int lde,
               int nkt)
{
    __shared__ ushort_t As[128 * 32];
    __shared__ ushort_t Bs[128 * 32];

    const int tid = threadIdx.x;
    const int w  = tid >> 6, l = tid & 63;
    const int lc = l & 31, q = l >> 5;
    const int wr = w >> 1, wc = w & 1;
    const int m0 = blockIdx.y * 128, n0 = blockIdx.x * 128;

    const int r0 = tid >> 2,         kc0 = (tid & 3) ^ ((r0 >> 1) & 3);
    const int r1 = (256 + tid) >> 2, kc1 = (tid & 3) ^ ((r1 >> 1) & 3);
    const ushort_t* gA0 = A  + (size_t)(m0 + r0) * lda + kc0 * 8;
    const ushort_t* gA1 = A  + (size_t)(m0 + r1) * lda + kc1 * 8;
    const ushort_t* gB0 = Bt + (size_t)(n0 + r0) * ldb + kc0 * 8;
    const ushort_t* gB1 = Bt + (size_t)(n0 + r1) * ldb + kc1 * 8;
    ushort_t* lA0 = &As[(w * 64) * 8];
    ushort_t* lA1 = &As[(256 + w * 64) * 8];
    ushort_t* lB0 = &Bs[(w * 64) * 8];
    ushort_t* lB1 = &Bs[(256 + w * 64) * 8];

    const int sl = (lc >> 1) & 3;
    const bf16x8* apt[2][2];
    const bf16x8* bpt[2][2];
    #pragma unroll
    for (int mi = 0; mi < 2; ++mi)
        #pragma unroll
        for (int ks = 0; ks < 2; ++ks) {
            const int kc = ks * 2 + q;
            const int mrow = wr * 64 + mi * 32 + lc;
            const int nrow = wc * 64 + mi * 32 + lc;
            apt[mi][ks] = (const bf16x8*)&As[(mrow * 4 + (kc ^ sl)) * 8];
            bpt[mi][ks] = (const bf16x8*)&Bs[(nrow * 4 + (kc ^ sl)) * 8];
        }

    f32x16 acc[2][2];
    #pragma unroll
    for (int mi = 0; mi < 2; ++mi)
        #pragma unroll
        for (int ni = 0; ni < 2; ++ni)
            #pragma unroll
            for (int e = 0; e < 16; ++e) acc[mi][ni][e] = 0.0f;

    for (int kt = 0; kt < nkt; ++kt) {
        async_copy16(lA0, gA0); async_copy16(lA1, gA1);
        async_copy16(lB0, gB0); async_copy16(lB1, gB1);
        gA0 += 32; gA1 += 32; gB0 += 32; gB1 += 32;
        __syncthreads();

        bf16x8 a[2][2], b[2][2];
        #pragma unroll
        for (int mi = 0; mi < 2; ++mi)
            #pragma unroll
            for (int ks = 0; ks < 2; ++ks) {
                a[mi][ks] = *apt[mi][ks];
                b[mi][ks] = *bpt[mi][ks];
            }
        #pragma unroll
        for (int ks = 0; ks < 2; ++ks)
            #pragma unroll
            for (int mi = 0; mi < 2; ++mi)
                #pragma unroll
                for (int ni = 0; ni < 2; ++ni)
                    acc[mi][ni] = __builtin_amdgcn_mfma_f32_32x32x16_bf16(
                        a[mi][ks], b[ni][ks], acc[mi][ni], 0, 0, 0);
        __syncthreads();
    }

    #pragma unroll
    for (int ni = 0; ni < 2; ++ni) {
        const int col = n0 + wc * 64 + ni * 32 + lc;
        const float bbc = (EPI == 2) ? 0.0f : bias[col];
        #pragma unroll
        for (int mi = 0; mi < 2; ++mi) {
            #pragma unroll
            for (int r = 0; r < 16; ++r) {
                const int row = m0 + wr * 64 + mi * 32 + (r & 3) + 8 * (r >> 2) + 4 * q;
                float val = acc[mi][ni][r] + ((EPI == 2) ? bias[row] : bbc);
                if (EPI == 1) {
                    const float e = bf2f(((const ushort_t*)extra)[(size_t)row * lde + col]);
                    val = val / (1.0f + expf(-val)) * e;
                    ((ushort_t*)Cv)[(size_t)row * ldc + col] = (ushort_t)f2bf(val);
                } else if (EPI == 2) {
                    const int bcol = col >> 11, tcol = col & 2047;
                    const int hrow = row >> 8, vrow = row & 255;
                    ((ushort_t*)Cv)[((size_t)(((bcol << 3) + hrow) * 256 + vrow)) * 2048 + tcol]
                        = (ushort_t)f2bf(val);
                } else {
                    ((float*)Cv)[(size_t)row * ldc + col] = val;
                }
            }
        }
    }
}

// ---------------------------------------------------------------------------
// QK GEMM with fused xpos + gamma^{+-(t&63)} epilogue -> qh, kh bf16
// A = hs_bf [4096][1024], Bt = wqkv_t rows [0,2048). Rotation pair = lane^1.
// ---------------------------------------------------------------------------
__global__ __launch_bounds__(256)
void gemm_qk(const ushort_t* __restrict__ A,
             const ushort_t* __restrict__ Bt,
             const float* __restrict__ bias,
             ushort_t* __restrict__ qh, ushort_t* __restrict__ kh)
{
    __shared__ ushort_t As[128 * 32];
    __shared__ ushort_t Bs[128 * 32];

    const int tid = threadIdx.x;
    const int w  = tid >> 6, l = tid & 63;
    const int lc = l & 31, q = l >> 5;
    const int wr = w >> 1, wc = w & 1;
    const int m0 = blockIdx.y * 128, n0 = blockIdx.x * 128;

    const int r0 = tid >> 2,         kc0 = (tid & 3) ^ ((r0 >> 1) & 3);
    const int r1 = (256 + tid) >> 2, kc1 = (tid & 3) ^ ((r1 >> 1) & 3);
    const ushort_t* gA0 = A  + (size_t)(m0 + r0) * E_DIM + kc0 * 8;
    const ushort_t* gA1 = A  + (size_t)(m0 + r1) * E_DIM + kc1 * 8;
    const ushort_t* gB0 = Bt + (size_t)(n0 + r0) * E_DIM + kc0 * 8;
    const ushort_t* gB1 = Bt + (size_t)(n0 + r1) * E_DIM + kc1 * 8;
    ushort_t* lA0 = &As[(w * 64) * 8];
    ushort_t* lA1 = &As[(256 + w * 64) * 8];
    ushort_t* lB0 = &Bs[(w * 64) * 8];
    ushort_t* lB1 = &Bs[(256 + w * 64) * 8];

    const int sl = (lc >> 1) & 3;
    const bf16x8* apt[2][2];
    const bf16x8* bpt[2][2];
    #pragma unroll
    for (int mi = 0; mi < 2; ++mi)
        #pragma unroll
        for (int ks = 0; ks < 2; ++ks) {
            const int kc = ks * 2 + q;
            const int mrow = wr * 64 + mi * 32 + lc;
            const int nrow = wc * 64 + mi * 32 + lc;
            apt[mi][ks] = (const bf16x8*)&As[(mrow * 4 + (kc ^ sl)) * 8];
            bpt[mi][ks] = (const bf16x8*)&Bs[(nrow * 4 + (kc ^ sl)) * 8];
        }

    f32x16 acc[2][2];
    #pragma unroll
    for (int mi = 0; mi < 2; ++mi)
        #pragma unroll
        for (int ni = 0; ni < 2; ++ni)
            #pragma unroll
            for (int e = 0; e < 16; ++e) acc[mi][ni][e] = 0.0f;

    for (int kt = 0; kt < E_DIM / 32; ++kt) {
        async_copy16(lA0, gA0); async_copy16(lA1, gA1);
        async_copy16(lB0, gB0); async_copy16(lB1, gB1);
        gA0 += 32; gA1 += 32; gB0 += 32; gB1 += 32;
        __syncthreads();

        bf16x8 a[2][2], b[2][2];
        #pragma unroll
        for (int mi = 0; mi < 2; ++mi)
            #pragma unroll
            for (int ks = 0; ks < 2; ++ks) {
                a[mi][ks] = *apt[mi][ks];
                b[mi][ks] = *bpt[mi][ks];
            }
        #pragma unroll
        for (int ks = 0; ks < 2; ++ks)
            #pragma unroll
            for (int mi = 0; mi < 2; ++mi)
                #pragma unroll
                for (int ni = 0; ni < 2; ++ni)
                    acc[mi][ni] = __builtin_amdgcn_mfma_f32_32x32x16_bf16(
                        a[mi][ks], b[ni][ks], acc[mi][ni], 0, 0, 0);
        __syncthreads();
    }

    // ---- fused xpos epilogue ----
    #pragma unroll
    for (int ni = 0; ni < 2; ++ni) {
        const int col = n0 + wc * 64 + ni * 32 + lc;      // 0..2047
        const bool isK = col >= 1024;
        const int hcol = col & 1023;
        const int h = hcol >> 7, d = hcol & 127;
        const int ip = hcol >> 1;
        float ld, gamma; decay_params(h, ld, gamma);
        const float sgn  = isK ? -1.0f : 1.0f;
        const float l2sv = log2f((2.0f * (float)ip + 409.6f) * (1.0f / 1433.6f))
                           * (1.0f / 512.0f) * sgn;
        const float invf = exp2f(-13.287712379549449f * (float)ip * (1.0f / 512.0f));
        const float bb   = bias[col];
        const float lds_ = ld * sgn;
        ushort_t* dst = isK ? kh : qh;
        #pragma unroll
        for (int mi = 0; mi < 2; ++mi) {
            #pragma unroll
            for (int r = 0; r < 16; ++r) {
                const int row = m0 + wr * 64 + mi * 32 + (r & 3) + 8 * (r >> 2) + 4 * q;
                const int t = row & (T_SEQ - 1), b = row >> 11;
                float val = acc[mi][ni][r] + bb;
                float part = __shfl_xor(val, 1);
                float sc  = exp2f(l2sv * (float)t);
                float gsc = expf(lds_ * (float)(t & 63));
                float sn, cs; sincosf((float)t * invf, &sn, &cs);
                float fc = cs * sc * gsc, fs = sn * sc * gsc;
                float o = (col & 1) ? (val * fc + part * fs) : (val * fc - part * fs);
                dst[((size_t)((b * 8 + h) * T_SEQ + t)) * 128 + d] = (ushort_t)f2bf(o);
            }
        }
    }
}

// ---------------------------------------------------------------------------
// TM=64 GEMM (for proj: N=1024 -> 512 blocks). fp32 out + bias[col].
// ---------------------------------------------------------------------------
__global__ __launch_bounds__(256)
void gemm_tm64(const ushort_t* __restrict__ A, int lda,
               const ushort_t* __restrict__ Bt, int ldb,
               const float* __restrict__ bias,
               float* __restrict__ C, int ldc, int nkt)
{
    __shared__ ushort_t As[64 * 32];
    __shared__ ushort_t Bs[128 * 32];

    const int tid = threadIdx.x;
    const int w  = tid >> 6, l = tid & 63;
    const int lc = l & 31, q = l >> 5;
    const int wr = w >> 1, wc = w & 1;
    const int m0 = blockIdx.y * 64, n0 = blockIdx.x * 128;

    const int rA = tid >> 2,         kcA = (tid & 3) ^ ((rA >> 1) & 3);
    const int rB0 = tid >> 2,        kcB0 = kcA;
    const int rB1 = (256 + tid) >> 2, kcB1 = (tid & 3) ^ ((rB1 >> 1) & 3);
    const ushort_t* gA  = A  + (size_t)(m0 + rA)  * lda + kcA  * 8;
    const ushort_t* gB0 = Bt + (size_t)(n0 + rB0) * ldb + kcB0 * 8;
    const ushort_t* gB1 = Bt + (size_t)(n0 + rB1) * ldb + kcB1 * 8;
    ushort_t* lA  = &As[(w * 64) * 8];
    ushort_t* lB0 = &Bs[(w * 64) * 8];
    ushort_t* lB1 = &Bs[(256 + w * 64) * 8];

    const int sl = (lc >> 1) & 3;
    const bf16x8* apt[2];
    const bf16x8* bpt[2][2];
    #pragma unroll
    for (int ks = 0; ks < 2; ++ks) {
        const int kc = ks * 2 + q;
        const int mrow = wr * 32 + lc;
        apt[ks] = (const bf16x8*)&As[(mrow * 4 + (kc ^ sl)) * 8];
        #pragma unroll
        for (int ni = 0; ni < 2; ++ni) {
            const int nrow = wc * 64 + ni * 32 + lc;
            bpt[ni][ks] = (const bf16x8*)&Bs[(nrow * 4 + (kc ^ sl)) * 8];
        }
    }

    f32x16 acc[2];
    #pragma unroll
    for (int ni = 0; ni < 2; ++ni)
        #pragma unroll
        for (int e = 0; e < 16; ++e) acc[ni][e] = 0.0f;

    for (int kt = 0; kt < nkt; ++kt) {
        async_copy16(lA, gA);
        async_copy16(lB0, gB0); async_copy16(lB1, gB1);
        gA += 32; gB0 += 32; gB1 += 32;
        __syncthreads();
        bf16x8 a[2], b[2][2];
        #pragma unroll
        for (int ks = 0; ks < 2; ++ks) {
            a[ks] = *apt[ks];
            b[0][ks] = *bpt[0][ks];
            b[1][ks] = *bpt[1][ks];
        }
        #pragma unroll
        for (int ks = 0; ks < 2; ++ks)
            #pragma unroll
            for (int ni = 0; ni < 2; ++ni)
                acc[ni] = __builtin_amdgcn_mfma_f32_32x32x16_bf16(
                    a[ks], b[ni][ks], acc[ni], 0, 0, 0);
        __syncthreads();
    }

    #pragma unroll
    for (int ni = 0; ni < 2; ++ni) {
        const int col = n0 + wc * 64 + ni * 32 + lc;
        const float bb = bias[col];
        #pragma unroll
        for (int r = 0; r < 16; ++r) {
            const int row = m0 + wr * 32 + (r & 3) + 8 * (r >> 2) + 4 * q;
            C[(size_t)row * ldc + col] = acc[ni][r] + bb;
        }
    }
}

// ---------------------------------------------------------------------------
// kt2 = gamma^63 * kh^T per head: [bh][T][128] -> [bh][128][T]
// ---------------------------------------------------------------------------
__global__ __launch_bounds__(256)
void kt2_kernel(const ushort_t* __restrict__ kh, ushort_t* __restrict__ kt2)
{
    __shared__ ushort_t tile[32][40];
    const int j0 = blockIdx.x * 32;
    const int zz = blockIdx.y;
    const int bh = zz >> 2, k0 = (zz & 3) * 32;
    const int t = threadIdx.x;
    const int r = t >> 3, c = (t & 7) * 4;
    float ld, gamma; decay_params(bh & 7, ld, gamma);
    const float g63 = expf(ld * 63.0f);
    *(u16x4*)&tile[r][c] = *(const u16x4*)&kh[((size_t)bh * T_SEQ + j0 + r) * 128 + k0 + c];
    __syncthreads();
    u16x4 o;
    o[0] = (ushort_t)f2bf(bf2f(tile[c][r])     * g63);
    o[1] = (ushort_t)f2bf(bf2f(tile[c + 1][r]) * g63);
    o[2] = (ushort_t)f2bf(bf2f(tile[c + 2][r]) * g63);
    o[3] = (ushort_t)f2bf(bf2f(tile[c + 3][r]) * g63);
    *(u16x4*)&kt2[((size_t)bh * 128 + k0 + r) * T_SEQ + j0 + c] = o;
}

// ---------------------------------------------------------------------------
// Phase A: A_c[v][k] = sum_{j in chunk} vt[v][j] * kt2[k][j]  (bf16)
// ---------------------------------------------------------------------------
__global__ __launch_bounds__(256)
void chunk_kv(const ushort_t* __restrict__ vt, const ushort_t* __restrict__ kt2,
              ushort_t* __restrict__ Abuf)
{
    const int c = blockIdx.x;
    const int bh = blockIdx.y;
    const int tid = threadIdx.x;
    const int w = tid >> 6, l = tid & 63, lc = l & 31, q = l >> 5;
    const int j0 = c * 64;

    f32x16 acc[2][4];
    #pragma unroll
    for (int mi = 0; mi < 2; ++mi)
        #pragma unroll
        for (int ni = 0; ni < 4; ++ni)
            #pragma unroll
            for (int e = 0; e < 16; ++e) acc[mi][ni][e] = 0.0f;

    #pragma unroll
    for (int ks = 0; ks < 4; ++ks) {
        bf16x8 a[2], bfr[4];
        #pragma unroll
        for (int mi = 0; mi < 2; ++mi)
            a[mi] = *(const bf16x8*)(vt + ((size_t)bh * 256 + w * 64 + mi * 32 + lc) * T_SEQ
                                     + j0 + ks * 16 + q * 8);
        #pragma unroll
        for (int ni = 0; ni < 4; ++ni)
            bfr[ni] = *(const bf16x8*)(kt2 + ((size_t)bh * 128 + ni * 32 + lc) * T_SEQ
                                       + j0 + ks * 16 + q * 8);
        #pragma unroll
        for (int mi = 0; mi < 2; ++mi)
            #pragma unroll
            for (int ni = 0; ni < 4; ++ni)
                acc[mi][ni] = __builtin_amdgcn_mfma_f32_32x32x16_bf16(
                    a[mi], bfr[ni], acc[mi][ni], 0, 0, 0);
    }

    ushort_t* ab = Abuf + (size_t)(bh * 32 + c) * 256 * 128;
    #pragma unroll
    for (int mi = 0; mi < 2; ++mi)
        #pragma unroll
        for (int ni = 0; ni < 4; ++ni)
            #pragma unroll
            for (int r = 0; r < 16; ++r) {
                const int v = w * 64 + mi * 32 + (r & 3) + 8 * (r >> 2) + 4 * q;
                const int k = ni * 32 + lc;
                ab[(size_t)v * 128 + k] = (ushort_t)f2bf(acc[mi][ni][r]);
            }
}

// ---------------------------------------------------------------------------
// Phase B: in-place scan: AS[c] := gamma*S_c (read A_c first);
// S_{c+1} = g64*S_c + A_c. Final state -> curr_kv (fp32).
// ---------------------------------------------------------------------------
__global__ __launch_bounds__(256)
void scan_state(ushort_t* __restrict__ AS, float* __restrict__ ckv)
{
    const int blk = blockIdx.x;
    const int bh = blk >> 7, sub = blk & 127;
    const int tid = threadIdx.x;
    const int v = sub * 2 + (tid >> 7), k = tid & 127;

    float ld, gamma;
    decay_params(bh & 7, ld, gamma);
    const float g64 = expf(ld * 64.0f);

    const size_t base = ((size_t)bh * 32 * 256 + v) * 128 + k;
    const size_t cstr = 256 * 128;
    float s = 0.0f;
    for (int c = 0; c < 32; ++c) {
        const size_t off = base + (size_t)c * cstr;
        float a = bf2f(AS[off]);
        AS[off] = (ushort_t)f2bf(gamma * s);
        s = g64 * s + a;
    }
    const float inv_scale = rsqrtf((1.0f - expf(ld * (float)T_SEQ)) / (1.0f - gamma));
    ckv[((size_t)bh * 128 + k) * 256 + v] = s * inv_scale;
}

// ---------------------------------------------------------------------------
// Phase C: per-i-tile output, single-wave blocks, fused groupnorm -> bf16.
// ---------------------------------------------------------------------------
__global__ __launch_bounds__(64)
void retention_chunk(const ushort_t* __restrict__ qh,
                     const ushort_t* __restrict__ kh,
                     const ushort_t* __restrict__ vt,
                     const ushort_t* __restrict__ St,
                     ushort_t* __restrict__ normed)
{
    const int it = blockIdx.x;
    const int bh = blockIdx.y;
    const int b = bh >> 3, h = bh & 7;
    const int c = it >> 1, w = it & 1;
    const int l = threadIdx.x, lc = l & 31, q = l >> 5;
    const int i0 = it * 32;
    const size_t bhT = (size_t)bh * T_SEQ;

    float ld, gamma;
    decay_params(h, ld, gamma);

    bf16x8 qf[8];
    {
        const ushort_t* qp = qh + (bhT + i0 + lc) * 128 + q * 8;
        #pragma unroll
        for (int c8 = 0; c8 < 8; ++c8)
            qf[c8] = *(const bf16x8*)(qp + c8 * 16);
    }

    f32x16 acc[8];
    #pragma unroll
    for (int vg = 0; vg < 8; ++vg)
        #pragma unroll
        for (int e = 0; e < 16; ++e) acc[vg][e] = 0.0f;

    if (c > 0) {
        const ushort_t* sp = St + ((size_t)(bh * 32 + c) * 256 + lc) * 128 + q * 8;
        #pragma unroll
        for (int vg = 0; vg < 8; ++vg) {
            const ushort_t* spv = sp + (size_t)vg * 32 * 128;
            #pragma unroll
            for (int ks = 0; ks < 8; ++ks) {
                bf16x8 sb = *(const bf16x8*)(spv + ks * 16);
                acc[vg] = __builtin_amdgcn_mfma_f32_32x32x16_bf16(
                    qf[ks], sb, acc[vg], 0, 0, 0);
            }
        }
    }

    for (int jt2 = 0; jt2 <= w; ++jt2) {
        const int j0 = c * 64 + jt2 * 32;

        f32x16 s;
        #pragma unroll
        for (int e = 0; e < 16; ++e) s[e] = 0.0f;
        const ushort_t* kp = kh + (bhT + j0 + lc) * 128 + q * 8;
        #pragma unroll
        for (int c8 = 0; c8 < 8; ++c8) {
            bf16x8 ka = *(const bf16x8*)(kp + c8 * 16);
            s = __builtin_amdgcn_mfma_f32_32x32x16_bf16(ka, qf[c8], s, 0, 0, 0);
        }

        float sv[16];
        #pragma unroll
        for (int r = 0; r < 16; ++r) {
            float val = s[r];
            if (jt2 == w) {
                int jr_ = (r & 3) + 8 * (r >> 2) + 4 * q;
                val = (jr_ <= lc) ? val : 0.0f;
            }
            sv[r] = val;
        }

        bf16x8 pa0, pa1;
        #pragma unroll
        for (int e = 0; e < 4; ++e) {
            float t1 = __shfl_xor(sv[e + 4], 32);
            float t0 = __shfl_xor(sv[e], 32);
            pa0[e]     = f2bf(q ? t1 : sv[e]);
            pa0[e + 4] = f2bf(q ? sv[e + 4] : t0);
            float t3 = __shfl_xor(sv[e + 12], 32);
            float t2 = __shfl_xor(sv[e + 8], 32);
            pa1[e]     = f2bf(q ? t3 : sv[e + 8]);
            pa1[e + 4] = f2bf(q ? sv[e + 12] : t2);
        }

        #pragma unroll
        for (int vg = 0; vg < 8; ++vg) {
            const ushort_t* vp = vt + ((size_t)bh * 256 + vg * 32 + lc) * T_SEQ + j0 + q * 8;
            bf16x8 vb0 = *(const bf16x8*)vp;
            bf16x8 vb1 = *(const bf16x8*)(vp + 16);
            acc[vg] = __builtin_amdgcn_mfma_f32_32x32x16_bf16(pa0, vb0, acc[vg], 0, 0, 0);
            acc[vg] = __builtin_amdgcn_mfma_f32_32x32x16_bf16(pa1, vb1, acc[vg], 0, 0, 0);
        }
    }

    #pragma unroll
    for (int r = 0; r < 16; ++r) {
        const int il = (r & 3) + 8 * (r >> 2) + 4 * q;
        const int i  = i0 + il;
        float denom = (1.0f - expf(ld * (float)(i + 1))) / (1.0f - gamma);
        float fs = 0.08838834764831845f * rsqrtf(denom);
        float vals[8];
        float a1 = 0.0f, a2 = 0.0f;
        #pragma unroll
        for (int vg = 0; vg < 8; ++vg) {
            float x = acc[vg][r] * fs;
            vals[vg] = x;
            a1 += x; a2 += x * x;
        }
        a1 += __shfl_xor(a1, 1);  a2 += __shfl_xor(a2, 1);
        a1 += __shfl_xor(a1, 2);  a2 += __shfl_xor(a2, 2);
        a1 += __shfl_xor(a1, 4);  a2 += __shfl_xor(a2, 4);
        a1 += __shfl_xor(a1, 8);  a2 += __shfl_xor(a2, 8);
        a1 += __shfl_xor(a1, 16); a2 += __shfl_xor(a2, 16);
        float mu = a1 * (1.0f / 256.0f);
        float var = a2 * (1.0f / 256.0f) - mu * mu;
        float rs = rsqrtf(var + 1e-5f);
        ushort_t* op = normed + ((size_t)(b * T_SEQ + i)) * V_DIM + h * DV + lc;
        #pragma unroll
        for (int vg = 0; vg < 8; ++vg)
            op[vg * 32] = (ushort_t)f2bf((vals[vg] - mu) * rs);
    }
}

// ---------------------------------------------------------------------------
extern "C" void kernel_launch(void* const* d_in, const int* in_sizes, int n_in,
                              void* d_out, int out_size, void* d_ws, size_t ws_size,
                              hipStream_t stream)
{
    const float* hs    = (const float*)d_in[0];
    const float* w_qkv = (const float*)d_in[1];
    const float* b_qkv = (const float*)d_in[2];
    const float* w_g   = (const float*)d_in[3];
    const float* b_g   = (const float*)d_in[4];
    const float* w_p   = (const float*)d_in[5];
    const float* b_p   = (const float*)d_in[6];
    float* out = (float*)d_out;

    const size_t MB = 1024 * 1024;
    // ws layout (96 MiB), lifetime-disjoint aliases:
    ushort_t* qh       = (ushort_t*)d_ws;                        // [0,8)
    ushort_t* kh       = (ushort_t*)((char*)d_ws +  8 * MB);     // [8,16)
    ushort_t* vt       = (ushort_t*)((char*)d_ws + 16 * MB);     // [16,32)  -> gated_bf after
    ushort_t* gated_bf = (ushort_t*)((char*)d_ws + 16 * MB);
    ushort_t* kt2      = (ushort_t*)((char*)d_ws + 32 * MB);     // [32,40)  -> wg_t/wp_t after
    ushort_t* wg_t     = (ushort_t*)((char*)d_ws + 32 * MB);
    ushort_t* wp_t     = (ushort_t*)((char*)d_ws + 36 * MB);
    ushort_t* AS       = (ushort_t*)((char*)d_ws + 40 * MB);     // [40,72)  Abuf / St in place
    ushort_t* wqkv_t   = (ushort_t*)((char*)d_ws + 72 * MB);     // [72,80)  -> normed after
    ushort_t* normed   = (ushort_t*)((char*)d_ws + 72 * MB);     // [72,88)
    ushort_t* hs_bf    = (ushort_t*)((char*)d_ws + 88 * MB);     // [88,96)
    float*    ckv_out  = out + (size_t)BT * E_DIM;

    // 1. conversions
    f32_to_bf16_kernel<<<dim3(2048), 256, 0, stream>>>(hs, hs_bf);
    transpose_w_kernel<<<dim3(128, 32), 256, 0, stream>>>(w_qkv, wqkv_t, E_DIM, 4096);

    // 2. QK GEMM with fused xpos/decay -> qh, kh (bf16)
    gemm_qk<<<dim3(16, 32), 256, 0, stream>>>(hs_bf, wqkv_t, b_qkv, qh, kh);

    // 3. V GEMM transposed -> vt [bh][256][T] (bf16) directly
    gemm_bf16<2><<<dim3(32, 16), 256, 0, stream>>>(
        wqkv_t + (size_t)2048 * E_DIM, E_DIM, hs_bf, E_DIM, b_qkv + 2048,
        vt, 2048, nullptr, 0, E_DIM / 32);

    // 4. kt2 = gamma^63 * kh^T
    kt2_kernel<<<dim3(64, 64), 256, 0, stream>>>(kh, kt2);

    // 5. chunked retention
    chunk_kv<<<dim3(32, 16), 256, 0, stream>>>(vt, kt2, AS);
    scan_state<<<dim3(2048), 256, 0, stream>>>(AS, ckv_out);
    retention_chunk<<<dim3(64, 16), 64, 0, stream>>>(qh, kh, vt, AS, normed);

    // 6. weight transposes for the tail GEMMs (kt2 region now dead)
    transpose_w_kernel<<<dim3(64, 32), 256, 0, stream>>>(w_g, wg_t, E_DIM, V_DIM);
    transpose_w_kernel<<<dim3(32, 64), 256, 0, stream>>>(w_p, wp_t, V_DIM, E_DIM);

    // 7. gated = silu(hs @ w_g + b_g) * normed -> bf16 (vt region dead)
    gemm_bf16<1><<<dim3(16, 32), 256, 0, stream>>>(
        hs_bf, E_DIM, wg_t, E_DIM, b_g, gated_bf, V_DIM, normed, V_DIM, E_DIM / 32);

    // 8. proj = gated @ w_p + b_p (TM=64 -> 512 blocks)
    gemm_tm64<<<dim3(8, 64), 256, 0, stream>>>(
        gated_bf, V_DIM, wp_t, V_DIM, b_p, out, E_DIM, V_DIM / 32);
}

// Round 7
// 433.244 us; speedup vs baseline: 1.3321x; 1.3321x over previous
//
#include <hip/hip_runtime.h>
#include <math.h>

#define BT      4096
#define T_SEQ   2048
#define E_DIM   1024
#define V_DIM   2048
#define DK      128
#define DV      256

typedef unsigned short ushort_t;
typedef __attribute__((ext_vector_type(8)))  short bf16x8;
typedef __attribute__((ext_vector_type(4)))  unsigned short u16x4;
typedef __attribute__((ext_vector_type(16))) float f32x16;

__device__ __forceinline__ void decay_params(int h, float& ld, float& gamma) {
    const float s0 = -3.4657359027997265f;  // ln(1/32)
    const float e0 = -6.2383246250395092f;  // ln(1/512)
    float lin = s0 + (e0 - s0) * ((float)h * (1.0f / 7.0f));
    gamma = 1.0f - expf(lin);
    ld = logf(gamma);
}

__device__ __forceinline__ short f2bf(float f) {
    unsigned u = __float_as_uint(f);
    unsigned r = (u + 0x7fffu + ((u >> 16) & 1u)) >> 16;
    return (short)r;
}
__device__ __forceinline__ float bf2f(ushort_t u) {
    return __uint_as_float((unsigned)u << 16);
}

__device__ __forceinline__ void async_copy16(void* lds, const void* g) {
    __builtin_amdgcn_global_load_lds(
        (const __attribute__((address_space(1))) unsigned int*)g,
        (__attribute__((address_space(3))) unsigned int*)lds, 16, 0, 0);
}

// ---------------------------------------------------------------------------
// fp32 -> bf16 elementwise
// ---------------------------------------------------------------------------
__global__ __launch_bounds__(256)
void f32_to_bf16_kernel(const float* __restrict__ in, ushort_t* __restrict__ out)
{
    int i = (blockIdx.x * 256 + threadIdx.x) * 8;
    float4 a = *(const float4*)&in[i];
    float4 b = *(const float4*)&in[i + 4];
    bf16x8 o;
    o[0] = f2bf(a.x); o[1] = f2bf(a.y); o[2] = f2bf(a.z); o[3] = f2bf(a.w);
    o[4] = f2bf(b.x); o[5] = f2bf(b.y); o[6] = f2bf(b.z); o[7] = f2bf(b.w);
    *(bf16x8*)&out[i] = o;
}

// ---------------------------------------------------------------------------
// W[K][N] fp32 -> Wt[N][K] bf16
// ---------------------------------------------------------------------------
__global__ __launch_bounds__(256)
void transpose_w_kernel(const float* __restrict__ W, ushort_t* __restrict__ Wt,
                        int K, int N)
{
    __shared__ float tile[32][33];
    const int k0 = blockIdx.y * 32, n0 = blockIdx.x * 32;
    const int t = threadIdx.x;
    const int r = t >> 3, c = (t & 7) * 4;
    float4 v = *(const float4*)&W[(size_t)(k0 + r) * N + n0 + c];
    tile[r][c] = v.x; tile[r][c + 1] = v.y; tile[r][c + 2] = v.z; tile[r][c + 3] = v.w;
    __syncthreads();
    u16x4 o;
    o[0] = (ushort_t)f2bf(tile[c][r]);
    o[1] = (ushort_t)f2bf(tile[c + 1][r]);
    o[2] = (ushort_t)f2bf(tile[c + 2][r]);
    o[3] = (ushort_t)f2bf(tile[c + 3][r]);
    *(u16x4*)&Wt[(size_t)(n0 + r) * K + k0 + c] = o;
}

// ---------------------------------------------------------------------------
// bf16 MFMA GEMM, 128x128 tile, BK=32, LDS-staged dense-store epilogues.
// EPI 1: bf16 out = silu(acc + bias[col]) * bf2f(extra[row][col]), C row-major
// EPI 2: bf16 out in vt layout [b*8+h][vfeat][token]; bias indexed by row.
// ---------------------------------------------------------------------------
template<int EPI>
__global__ __launch_bounds__(256)
void gemm_bf16(const ushort_t* __restrict__ A, int lda,
               const ushort_t* __restrict__ Bt, int ldb,
               const float* __restrict__ bias,
               void* __restrict__ Cv, int ldc,
               const void* __restrict__ extra, int lde,
               int nkt)
{
    __shared__ ushort_t Sh[17408];          // staging (16KB) + out tile 128x136 (34KB)
    ushort_t* As = Sh;
    ushort_t* Bs = Sh + 4096;

    const int tid = threadIdx.x;
    const int w  = tid >> 6, l = tid & 63;
    const int lc = l & 31, q = l >> 5;
    const int wr = w >> 1, wc = w & 1;
    const int m0 = blockIdx.y * 128, n0 = blockIdx.x * 128;

    const int r0 = tid >> 2,         kc0 = (tid & 3) ^ ((r0 >> 1) & 3);
    const int r1 = (256 + tid) >> 2, kc1 = (tid & 3) ^ ((r1 >> 1) & 3);
    const ushort_t* gA0 = A  + (size_t)(m0 + r0) * lda + kc0 * 8;
    const ushort_t* gA1 = A  + (size_t)(m0 + r1) * lda + kc1 * 8;
    const ushort_t* gB0 = Bt + (size_t)(n0 + r0) * ldb + kc0 * 8;
    const ushort_t* gB1 = Bt + (size_t)(n0 + r1) * ldb + kc1 * 8;
    ushort_t* lA0 = &As[(w * 64) * 8];
    ushort_t* lA1 = &As[(256 + w * 64) * 8];
    ushort_t* lB0 = &Bs[(w * 64) * 8];
    ushort_t* lB1 = &Bs[(256 + w * 64) * 8];

    const int sl = (lc >> 1) & 3;
    const bf16x8* apt[2][2];
    const bf16x8* bpt[2][2];
    #pragma unroll
    for (int mi = 0; mi < 2; ++mi)
        #pragma unroll
        for (int ks = 0; ks < 2; ++ks) {
            const int kc = ks * 2 + q;
            const int mrow = wr * 64 + mi * 32 + lc;
            const int nrow = wc * 64 + mi * 32 + lc;
            apt[mi][ks] = (const bf16x8*)&As[(mrow * 4 + (kc ^ sl)) * 8];
            bpt[mi][ks] = (const bf16x8*)&Bs[(nrow * 4 + (kc ^ sl)) * 8];
        }

    f32x16 acc[2][2];
    #pragma unroll
    for (int mi = 0; mi < 2; ++mi)
        #pragma unroll
        for (int ni = 0; ni < 2; ++ni)
            #pragma unroll
            for (int e = 0; e < 16; ++e) acc[mi][ni][e] = 0.0f;

    for (int kt = 0; kt < nkt; ++kt) {
        async_copy16(lA0, gA0); async_copy16(lA1, gA1);
        async_copy16(lB0, gB0); async_copy16(lB1, gB1);
        gA0 += 32; gA1 += 32; gB0 += 32; gB1 += 32;
        __syncthreads();

        bf16x8 a[2][2], b[2][2];
        #pragma unroll
        for (int mi = 0; mi < 2; ++mi)
            #pragma unroll
            for (int ks = 0; ks < 2; ++ks) {
                a[mi][ks] = *apt[mi][ks];
                b[mi][ks] = *bpt[mi][ks];
            }
        #pragma unroll
        for (int ks = 0; ks < 2; ++ks)
            #pragma unroll
            for (int mi = 0; mi < 2; ++mi)
                #pragma unroll
                for (int ni = 0; ni < 2; ++ni)
                    acc[mi][ni] = __builtin_amdgcn_mfma_f32_32x32x16_bf16(
                        a[mi][ks], b[ni][ks], acc[mi][ni], 0, 0, 0);
        __syncthreads();
    }

    if (EPI == 1) {
        #pragma unroll
        for (int ni = 0; ni < 2; ++ni) {
            const int col = n0 + wc * 64 + ni * 32 + lc;
            const float bbc = bias[col];
            #pragma unroll
            for (int mi = 0; mi < 2; ++mi)
                #pragma unroll
                for (int r = 0; r < 16; ++r) {
                    const int rl = wr * 64 + mi * 32 + (r & 3) + 8 * (r >> 2) + 4 * q;
                    const int row = m0 + rl;
                    float val = acc[mi][ni][r] + bbc;
                    const float e = bf2f(((const ushort_t*)extra)[(size_t)row * lde + col]);
                    val = val / (1.0f + expf(-val)) * e;
                    Sh[rl * 136 + wc * 64 + ni * 32 + lc] = (ushort_t)f2bf(val);
                }
        }
        __syncthreads();
        ushort_t* dstb = (ushort_t*)Cv + (size_t)m0 * ldc + n0;
        #pragma unroll
        for (int s = 0; s < 8; ++s) {
            const int e = s * 2048 + tid * 8;
            const int rl = e >> 7, cc = e & 127;
            *(bf16x8*)&dstb[(size_t)rl * ldc + cc] = *(const bf16x8*)&Sh[rl * 136 + cc];
        }
    } else {   // EPI == 2: vt layout
        #pragma unroll
        for (int ni = 0; ni < 2; ++ni) {
            const int tlc = wc * 64 + ni * 32 + lc;     // token_local
            #pragma unroll
            for (int mi = 0; mi < 2; ++mi)
                #pragma unroll
                for (int r = 0; r < 16; ++r) {
                    const int vl = wr * 64 + mi * 32 + (r & 3) + 8 * (r >> 2) + 4 * q;
                    float val = acc[mi][ni][r] + bias[m0 + vl];
                    Sh[vl * 136 + tlc] = (ushort_t)f2bf(val);
                }
        }
        __syncthreads();
        const int bh0 = ((n0 >> 11) << 3) + (m0 >> 8);
        const int vrow0 = m0 & 255, t0 = n0 & (T_SEQ - 1);
        ushort_t* dstb = (ushort_t*)Cv + ((size_t)bh0 * 256 + vrow0) * 2048 + t0;
        #pragma unroll
        for (int s = 0; s < 8; ++s) {
            const int e = s * 2048 + tid * 8;
            const int vl = e >> 7, tt = e & 127;
            *(bf16x8*)&dstb[(size_t)vl * 2048 + tt] = *(const bf16x8*)&Sh[vl * 136 + tt];
        }
    }
}

// ---------------------------------------------------------------------------
// QK GEMM with fused xpos + gamma^{+-(t&63)} epilogue -> qh, kh bf16.
// Output staged through LDS; each block stores a contiguous 32KB region
// with wave-contiguous 1KB stores (fixes round-6 write amplification).
// ---------------------------------------------------------------------------
__global__ __launch_bounds__(256)
void gemm_qk(const ushort_t* __restrict__ A,
             const ushort_t* __restrict__ Bt,
             const float* __restrict__ bias,
             ushort_t* __restrict__ qh, ushort_t* __restrict__ kh)
{
    __shared__ ushort_t Sh[17408];
    ushort_t* As = Sh;
    ushort_t* Bs = Sh + 4096;

    const int tid = threadIdx.x;
    const int w  = tid >> 6, l = tid & 63;
    const int lc = l & 31, q = l >> 5;
    const int wr = w >> 1, wc = w & 1;
    const int m0 = blockIdx.y * 128, n0 = blockIdx.x * 128;

    const int r0 = tid >> 2,         kc0 = (tid & 3) ^ ((r0 >> 1) & 3);
    const int r1 = (256 + tid) >> 2, kc1 = (tid & 3) ^ ((r1 >> 1) & 3);
    const ushort_t* gA0 = A  + (size_t)(m0 + r0) * E_DIM + kc0 * 8;
    const ushort_t* gA1 = A  + (size_t)(m0 + r1) * E_DIM + kc1 * 8;
    const ushort_t* gB0 = Bt + (size_t)(n0 + r0) * E_DIM + kc0 * 8;
    const ushort_t* gB1 = Bt + (size_t)(n0 + r1) * E_DIM + kc1 * 8;
    ushort_t* lA0 = &As[(w * 64) * 8];
    ushort_t* lA1 = &As[(256 + w * 64) * 8];
    ushort_t* lB0 = &Bs[(w * 64) * 8];
    ushort_t* lB1 = &Bs[(256 + w * 64) * 8];

    const int sl = (lc >> 1) & 3;
    const bf16x8* apt[2][2];
    const bf16x8* bpt[2][2];
    #pragma unroll
    for (int mi = 0; mi < 2; ++mi)
        #pragma unroll
        for (int ks = 0; ks < 2; ++ks) {
            const int kc = ks * 2 + q;
            const int mrow = wr * 64 + mi * 32 + lc;
            const int nrow = wc * 64 + mi * 32 + lc;
            apt[mi][ks] = (const bf16x8*)&As[(mrow * 4 + (kc ^ sl)) * 8];
            bpt[mi][ks] = (const bf16x8*)&Bs[(nrow * 4 + (kc ^ sl)) * 8];
        }

    f32x16 acc[2][2];
    #pragma unroll
    for (int mi = 0; mi < 2; ++mi)
        #pragma unroll
        for (int ni = 0; ni < 2; ++ni)
            #pragma unroll
            for (int e = 0; e < 16; ++e) acc[mi][ni][e] = 0.0f;

    for (int kt = 0; kt < E_DIM / 32; ++kt) {
        async_copy16(lA0, gA0); async_copy16(lA1, gA1);
        async_copy16(lB0, gB0); async_copy16(lB1, gB1);
        gA0 += 32; gA1 += 32; gB0 += 32; gB1 += 32;
        __syncthreads();

        bf16x8 a[2][2], b[2][2];
        #pragma unroll
        for (int mi = 0; mi < 2; ++mi)
            #pragma unroll
            for (int ks = 0; ks < 2; ++ks) {
                a[mi][ks] = *apt[mi][ks];
                b[mi][ks] = *bpt[mi][ks];
            }
        #pragma unroll
        for (int ks = 0; ks < 2; ++ks)
            #pragma unroll
            for (int mi = 0; mi < 2; ++mi)
                #pragma unroll
                for (int ni = 0; ni < 2; ++ni)
                    acc[mi][ni] = __builtin_amdgcn_mfma_f32_32x32x16_bf16(
                        a[mi][ks], b[ni][ks], acc[mi][ni], 0, 0, 0);
        __syncthreads();
    }

    // ---- fused xpos epilogue -> LDS tile [t_local][136] ----
    #pragma unroll
    for (int ni = 0; ni < 2; ++ni) {
        const int col = n0 + wc * 64 + ni * 32 + lc;      // 0..2047
        const bool isK = col >= 1024;
        const int hcol = col & 1023;
        const int h = hcol >> 7;
        const int ip = hcol >> 1;
        float ld, gamma; decay_params(h, ld, gamma);
        const float sgn  = isK ? -1.0f : 1.0f;
        const float l2sv = log2f((2.0f * (float)ip + 409.6f) * (1.0f / 1433.6f))
                           * (1.0f / 512.0f) * sgn;
        const float invf = exp2f(-13.287712379549449f * (float)ip * (1.0f / 512.0f));
        const float bb   = bias[col];
        const float lds_ = ld * sgn;
        #pragma unroll
        for (int mi = 0; mi < 2; ++mi) {
            #pragma unroll
            for (int r = 0; r < 16; ++r) {
                const int tl = wr * 64 + mi * 32 + (r & 3) + 8 * (r >> 2) + 4 * q;
                const int t = (m0 + tl) & (T_SEQ - 1);
                float val = acc[mi][ni][r] + bb;
                float part = __shfl_xor(val, 1);
                float sc  = exp2f(l2sv * (float)t);
                float gsc = expf(lds_ * (float)(t & 63));
                float sn, cs; sincosf((float)t * invf, &sn, &cs);
                float fc = cs * sc * gsc, fs = sn * sc * gsc;
                float o = (col & 1) ? (val * fc + part * fs) : (val * fc - part * fs);
                Sh[tl * 136 + wc * 64 + ni * 32 + lc] = (ushort_t)f2bf(o);
            }
        }
    }
    __syncthreads();
    // dense store: block's output is one contiguous 32KB region
    const int b0 = m0 >> 11, t0 = m0 & (T_SEQ - 1);
    const bool isK0 = (n0 >= 1024);
    const int h0 = (n0 & 1023) >> 7;
    ushort_t* dstb = (isK0 ? kh : qh) + ((size_t)(b0 * 8 + h0) * T_SEQ + t0) * 128;
    #pragma unroll
    for (int s = 0; s < 8; ++s) {
        const int e = s * 2048 + tid * 8;
        *(bf16x8*)&dstb[e] = *(const bf16x8*)&Sh[(e >> 7) * 136 + (e & 127)];
    }
}

// ---------------------------------------------------------------------------
// TM=64 GEMM (for proj: 512 blocks). fp32 out + bias[col] (4B/lane stores
// are full-line per half-wave — no staging needed).
// ---------------------------------------------------------------------------
__global__ __launch_bounds__(256)
void gemm_tm64(const ushort_t* __restrict__ A, int lda,
               const ushort_t* __restrict__ Bt, int ldb,
               const float* __restrict__ bias,
               float* __restrict__ C, int ldc, int nkt)
{
    __shared__ ushort_t As[64 * 32];
    __shared__ ushort_t Bs[128 * 32];

    const int tid = threadIdx.x;
    const int w  = tid >> 6, l = tid & 63;
    const int lc = l & 31, q = l >> 5;
    const int wr = w >> 1, wc = w & 1;
    const int m0 = blockIdx.y * 64, n0 = blockIdx.x * 128;

    const int rA = tid >> 2,          kcA = (tid & 3) ^ ((rA >> 1) & 3);
    const int rB1 = (256 + tid) >> 2, kcB1 = (tid & 3) ^ ((rB1 >> 1) & 3);
    const ushort_t* gA  = A  + (size_t)(m0 + rA)  * lda + kcA  * 8;
    const ushort_t* gB0 = Bt + (size_t)(n0 + rA)  * ldb + kcA  * 8;
    const ushort_t* gB1 = Bt + (size_t)(n0 + rB1) * ldb + kcB1 * 8;
    ushort_t* lA  = &As[(w * 64) * 8];
    ushort_t* lB0 = &Bs[(w * 64) * 8];
    ushort_t* lB1 = &Bs[(256 + w * 64) * 8];

    const int sl = (lc >> 1) & 3;
    const bf16x8* apt[2];
    const bf16x8* bpt[2][2];
    #pragma unroll
    for (int ks = 0; ks < 2; ++ks) {
        const int kc = ks * 2 + q;
        const int mrow = wr * 32 + lc;
        apt[ks] = (const bf16x8*)&As[(mrow * 4 + (kc ^ sl)) * 8];
        #pragma unroll
        for (int ni = 0; ni < 2; ++ni) {
            const int nrow = wc * 64 + ni * 32 + lc;
            bpt[ni][ks] = (const bf16x8*)&Bs[(nrow * 4 + (kc ^ sl)) * 8];
        }
    }

    f32x16 acc[2];
    #pragma unroll
    for (int ni = 0; ni < 2; ++ni)
        #pragma unroll
        for (int e = 0; e < 16; ++e) acc[ni][e] = 0.0f;

    for (int kt = 0; kt < nkt; ++kt) {
        async_copy16(lA, gA);
        async_copy16(lB0, gB0); async_copy16(lB1, gB1);
        gA += 32; gB0 += 32; gB1 += 32;
        __syncthreads();
        bf16x8 a[2], b[2][2];
        #pragma unroll
        for (int ks = 0; ks < 2; ++ks) {
            a[ks] = *apt[ks];
            b[0][ks] = *bpt[0][ks];
            b[1][ks] = *bpt[1][ks];
        }
        #pragma unroll
        for (int ks = 0; ks < 2; ++ks)
            #pragma unroll
            for (int ni = 0; ni < 2; ++ni)
                acc[ni] = __builtin_amdgcn_mfma_f32_32x32x16_bf16(
                    a[ks], b[ni][ks], acc[ni], 0, 0, 0);
        __syncthreads();
    }

    #pragma unroll
    for (int ni = 0; ni < 2; ++ni) {
        const int col = n0 + wc * 64 + ni * 32 + lc;
        const float bb = bias[col];
        #pragma unroll
        for (int r = 0; r < 16; ++r) {
            const int row = m0 + wr * 32 + (r & 3) + 8 * (r >> 2) + 4 * q;
            C[(size_t)row * ldc + col] = acc[ni][r] + bb;
        }
    }
}

// ---------------------------------------------------------------------------
// kt2 = gamma^63 * kh^T per head: [bh][T][128] -> [bh][128][T]
// ---------------------------------------------------------------------------
__global__ __launch_bounds__(256)
void kt2_kernel(const ushort_t* __restrict__ kh, ushort_t* __restrict__ kt2)
{
    __shared__ ushort_t tile[32][40];
    const int j0 = blockIdx.x * 32;
    const int zz = blockIdx.y;
    const int bh = zz >> 2, k0 = (zz & 3) * 32;
    const int t = threadIdx.x;
    const int r = t >> 3, c = (t & 7) * 4;
    float ld, gamma; decay_params(bh & 7, ld, gamma);
    const float g63 = expf(ld * 63.0f);
    *(u16x4*)&tile[r][c] = *(const u16x4*)&kh[((size_t)bh * T_SEQ + j0 + r) * 128 + k0 + c];
    __syncthreads();
    u16x4 o;
    o[0] = (ushort_t)f2bf(bf2f(tile[c][r])     * g63);
    o[1] = (ushort_t)f2bf(bf2f(tile[c + 1][r]) * g63);
    o[2] = (ushort_t)f2bf(bf2f(tile[c + 2][r]) * g63);
    o[3] = (ushort_t)f2bf(bf2f(tile[c + 3][r]) * g63);
    *(u16x4*)&kt2[((size_t)bh * 128 + k0 + r) * T_SEQ + j0 + c] = o;
}

// ---------------------------------------------------------------------------
// Phase A: A_c[v][k] = sum_{j in chunk} vt[v][j] * kt2[k][j]  (bf16)
// ---------------------------------------------------------------------------
__global__ __launch_bounds__(256)
void chunk_kv(const ushort_t* __restrict__ vt, const ushort_t* __restrict__ kt2,
              ushort_t* __restrict__ Abuf)
{
    const int c = blockIdx.x;
    const int bh = blockIdx.y;
    const int tid = threadIdx.x;
    const int w = tid >> 6, l = tid & 63, lc = l & 31, q = l >> 5;
    const int j0 = c * 64;

    f32x16 acc[2][4];
    #pragma unroll
    for (int mi = 0; mi < 2; ++mi)
        #pragma unroll
        for (int ni = 0; ni < 4; ++ni)
            #pragma unroll
            for (int e = 0; e < 16; ++e) acc[mi][ni][e] = 0.0f;

    #pragma unroll
    for (int ks = 0; ks < 4; ++ks) {
        bf16x8 a[2], bfr[4];
        #pragma unroll
        for (int mi = 0; mi < 2; ++mi)
            a[mi] = *(const bf16x8*)(vt + ((size_t)bh * 256 + w * 64 + mi * 32 + lc) * T_SEQ
                                     + j0 + ks * 16 + q * 8);
        #pragma unroll
        for (int ni = 0; ni < 4; ++ni)
            bfr[ni] = *(const bf16x8*)(kt2 + ((size_t)bh * 128 + ni * 32 + lc) * T_SEQ
                                       + j0 + ks * 16 + q * 8);
        #pragma unroll
        for (int mi = 0; mi < 2; ++mi)
            #pragma unroll
            for (int ni = 0; ni < 4; ++ni)
                acc[mi][ni] = __builtin_amdgcn_mfma_f32_32x32x16_bf16(
                    a[mi], bfr[ni], acc[mi][ni], 0, 0, 0);
    }

    ushort_t* ab = Abuf + (size_t)(bh * 32 + c) * 256 * 128;
    #pragma unroll
    for (int mi = 0; mi < 2; ++mi)
        #pragma unroll
        for (int ni = 0; ni < 4; ++ni)
            #pragma unroll
            for (int r = 0; r < 16; ++r) {
                const int v = w * 64 + mi * 32 + (r & 3) + 8 * (r >> 2) + 4 * q;
                const int k = ni * 32 + lc;
                ab[(size_t)v * 128 + k] = (ushort_t)f2bf(acc[mi][ni][r]);
            }
}

// ---------------------------------------------------------------------------
// Phase B: in-place scan: AS[c] := gamma*S_c (read A_c first);
// S_{c+1} = g64*S_c + A_c. Final state -> curr_kv (fp32).
// ---------------------------------------------------------------------------
__global__ __launch_bounds__(256)
void scan_state(ushort_t* __restrict__ AS, float* __restrict__ ckv)
{
    const int blk = blockIdx.x;
    const int bh = blk >> 7, sub = blk & 127;
    const int tid = threadIdx.x;
    const int v = sub * 2 + (tid >> 7), k = tid & 127;

    float ld, gamma;
    decay_params(bh & 7, ld, gamma);
    const float g64 = expf(ld * 64.0f);

    const size_t base = ((size_t)bh * 32 * 256 + v) * 128 + k;
    const size_t cstr = 256 * 128;
    float s = 0.0f;
    for (int c = 0; c < 32; ++c) {
        const size_t off = base + (size_t)c * cstr;
        float a = bf2f(AS[off]);
        AS[off] = (ushort_t)f2bf(gamma * s);
        s = g64 * s + a;
    }
    const float inv_scale = rsqrtf((1.0f - expf(ld * (float)T_SEQ)) / (1.0f - gamma));
    ckv[((size_t)bh * 128 + k) * 256 + v] = s * inv_scale;
}

// ---------------------------------------------------------------------------
// Phase C: per-i-tile output, single-wave blocks, fused groupnorm -> bf16.
// ---------------------------------------------------------------------------
__global__ __launch_bounds__(64)
void retention_chunk(const ushort_t* __restrict__ qh,
                     const ushort_t* __restrict__ kh,
                     const ushort_t* __restrict__ vt,
                     const ushort_t* __restrict__ St,
                     ushort_t* __restrict__ normed)
{
    const int it = blockIdx.x;
    const int bh = blockIdx.y;
    const int b = bh >> 3, h = bh & 7;
    const int c = it >> 1, w = it & 1;
    const int l = threadIdx.x, lc = l & 31, q = l >> 5;
    const int i0 = it * 32;
    const size_t bhT = (size_t)bh * T_SEQ;

    float ld, gamma;
    decay_params(h, ld, gamma);

    bf16x8 qf[8];
    {
        const ushort_t* qp = qh + (bhT + i0 + lc) * 128 + q * 8;
        #pragma unroll
        for (int c8 = 0; c8 < 8; ++c8)
            qf[c8] = *(const bf16x8*)(qp + c8 * 16);
    }

    f32x16 acc[8];
    #pragma unroll
    for (int vg = 0; vg < 8; ++vg)
        #pragma unroll
        for (int e = 0; e < 16; ++e) acc[vg][e] = 0.0f;

    if (c > 0) {
        const ushort_t* sp = St + ((size_t)(bh * 32 + c) * 256 + lc) * 128 + q * 8;
        #pragma unroll
        for (int vg = 0; vg < 8; ++vg) {
            const ushort_t* spv = sp + (size_t)vg * 32 * 128;
            #pragma unroll
            for (int ks = 0; ks < 8; ++ks) {
                bf16x8 sb = *(const bf16x8*)(spv + ks * 16);
                acc[vg] = __builtin_amdgcn_mfma_f32_32x32x16_bf16(
                    qf[ks], sb, acc[vg], 0, 0, 0);
            }
        }
    }

    for (int jt2 = 0; jt2 <= w; ++jt2) {
        const int j0 = c * 64 + jt2 * 32;

        f32x16 s;
        #pragma unroll
        for (int e = 0; e < 16; ++e) s[e] = 0.0f;
        const ushort_t* kp = kh + (bhT + j0 + lc) * 128 + q * 8;
        #pragma unroll
        for (int c8 = 0; c8 < 8; ++c8) {
            bf16x8 ka = *(const bf16x8*)(kp + c8 * 16);
            s = __builtin_amdgcn_mfma_f32_32x32x16_bf16(ka, qf[c8], s, 0, 0, 0);
        }

        float sv[16];
        #pragma unroll
        for (int r = 0; r < 16; ++r) {
            float val = s[r];
            if (jt2 == w) {
                int jr_ = (r & 3) + 8 * (r >> 2) + 4 * q;
                val = (jr_ <= lc) ? val : 0.0f;
            }
            sv[r] = val;
        }

        bf16x8 pa0, pa1;
        #pragma unroll
        for (int e = 0; e < 4; ++e) {
            float t1 = __shfl_xor(sv[e + 4], 32);
            float t0 = __shfl_xor(sv[e], 32);
            pa0[e]     = f2bf(q ? t1 : sv[e]);
            pa0[e + 4] = f2bf(q ? sv[e + 4] : t0);
            float t3 = __shfl_xor(sv[e + 12], 32);
            float t2 = __shfl_xor(sv[e + 8], 32);
            pa1[e]     = f2bf(q ? t3 : sv[e + 8]);
            pa1[e + 4] = f2bf(q ? sv[e + 12] : t2);
        }

        #pragma unroll
        for (int vg = 0; vg < 8; ++vg) {
            const ushort_t* vp = vt + ((size_t)bh * 256 + vg * 32 + lc) * T_SEQ + j0 + q * 8;
            bf16x8 vb0 = *(const bf16x8*)vp;
            bf16x8 vb1 = *(const bf16x8*)(vp + 16);
            acc[vg] = __builtin_amdgcn_mfma_f32_32x32x16_bf16(pa0, vb0, acc[vg], 0, 0, 0);
            acc[vg] = __builtin_amdgcn_mfma_f32_32x32x16_bf16(pa1, vb1, acc[vg], 0, 0, 0);
        }
    }

    #pragma unroll
    for (int r = 0; r < 16; ++r) {
        const int il = (r & 3) + 8 * (r >> 2) + 4 * q;
        const int i  = i0 + il;
        float denom = (1.0f - expf(ld * (float)(i + 1))) / (1.0f - gamma);
        float fs = 0.08838834764831845f * rsqrtf(denom);
        float vals[8];
        float a1 = 0.0f, a2 = 0.0f;
        #pragma unroll
        for (int vg = 0; vg < 8; ++vg) {
            float x = acc[vg][r] * fs;
            vals[vg] = x;
            a1 += x; a2 += x * x;
        }
        a1 += __shfl_xor(a1, 1);  a2 += __shfl_xor(a2, 1);
        a1 += __shfl_xor(a1, 2);  a2 += __shfl_xor(a2, 2);
        a1 += __shfl_xor(a1, 4);  a2 += __shfl_xor(a2, 4);
        a1 += __shfl_xor(a1, 8);  a2 += __shfl_xor(a2, 8);
        a1 += __shfl_xor(a1, 16); a2 += __shfl_xor(a2, 16);
        float mu = a1 * (1.0f / 256.0f);
        float var = a2 * (1.0f / 256.0f) - mu * mu;
        float rs = rsqrtf(var + 1e-5f);
        ushort_t* op = normed + ((size_t)(b * T_SEQ + i)) * V_DIM + h * DV + lc;
        #pragma unroll
        for (int vg = 0; vg < 8; ++vg)
            op[vg * 32] = (ushort_t)f2bf((vals[vg] - mu) * rs);
    }
}

// ---------------------------------------------------------------------------
extern "C" void kernel_launch(void* const* d_in, const int* in_sizes, int n_in,
                              void* d_out, int out_size, void* d_ws, size_t ws_size,
                              hipStream_t stream)
{
    const float* hs    = (const float*)d_in[0];
    const float* w_qkv = (const float*)d_in[1];
    const float* b_qkv = (const float*)d_in[2];
    const float* w_g   = (const float*)d_in[3];
    const float* b_g   = (const float*)d_in[4];
    const float* w_p   = (const float*)d_in[5];
    const float* b_p   = (const float*)d_in[6];
    float* out = (float*)d_out;

    const size_t MB = 1024 * 1024;
    // ws layout (96 MiB), lifetime-disjoint aliases:
    ushort_t* qh       = (ushort_t*)d_ws;                        // [0,8)
    ushort_t* kh       = (ushort_t*)((char*)d_ws +  8 * MB);     // [8,16)
    ushort_t* vt       = (ushort_t*)((char*)d_ws + 16 * MB);     // [16,32) -> gated_bf after
    ushort_t* gated_bf = (ushort_t*)((char*)d_ws + 16 * MB);
    ushort_t* kt2      = (ushort_t*)((char*)d_ws + 32 * MB);     // [32,40) -> wg_t/wp_t after
    ushort_t* wg_t     = (ushort_t*)((char*)d_ws + 32 * MB);
    ushort_t* wp_t     = (ushort_t*)((char*)d_ws + 36 * MB);
    ushort_t* AS       = (ushort_t*)((char*)d_ws + 40 * MB);     // [40,72)  Abuf / St in place
    ushort_t* wqkv_t   = (ushort_t*)((char*)d_ws + 72 * MB);     // [72,80) -> normed after
    ushort_t* normed   = (ushort_t*)((char*)d_ws + 72 * MB);     // [72,88)
    ushort_t* hs_bf    = (ushort_t*)((char*)d_ws + 88 * MB);     // [88,96)
    float*    ckv_out  = out + (size_t)BT * E_DIM;

    // 1. conversions
    f32_to_bf16_kernel<<<dim3(2048), 256, 0, stream>>>(hs, hs_bf);
    transpose_w_kernel<<<dim3(128, 32), 256, 0, stream>>>(w_qkv, wqkv_t, E_DIM, 4096);

    // 2. QK GEMM with fused xpos/decay -> qh, kh (bf16, dense stores)
    gemm_qk<<<dim3(16, 32), 256, 0, stream>>>(hs_bf, wqkv_t, b_qkv, qh, kh);

    // 3. V GEMM transposed -> vt [bh][256][T] (bf16, dense stores)
    gemm_bf16<2><<<dim3(32, 16), 256, 0, stream>>>(
        wqkv_t + (size_t)2048 * E_DIM, E_DIM, hs_bf, E_DIM, b_qkv + 2048,
        vt, 2048, nullptr, 0, E_DIM / 32);

    // 4. kt2 = gamma^63 * kh^T
    kt2_kernel<<<dim3(64, 64), 256, 0, stream>>>(kh, kt2);

    // 5. chunked retention
    chunk_kv<<<dim3(32, 16), 256, 0, stream>>>(vt, kt2, AS);
    scan_state<<<dim3(2048), 256, 0, stream>>>(AS, ckv_out);
    retention_chunk<<<dim3(64, 16), 64, 0, stream>>>(qh, kh, vt, AS, normed);

    // 6. weight transposes for the tail GEMMs (kt2 region now dead)
    transpose_w_kernel<<<dim3(64, 32), 256, 0, stream>>>(w_g, wg_t, E_DIM, V_DIM);
    transpose_w_kernel<<<dim3(32, 64), 256, 0, stream>>>(w_p, wp_t, V_DIM, E_DIM);

    // 7. gated = silu(hs @ w_g + b_g) * normed -> bf16 (vt region dead)
    gemm_bf16<1><<<dim3(16, 32), 256, 0, stream>>>(
        hs_bf, E_DIM, wg_t, E_DIM, b_g, gated_bf, V_DIM, normed, V_DIM, E_DIM / 32);

    // 8. proj = gated @ w_p + b_p (TM=64 -> 512 blocks)
    gemm_tm64<<<dim3(8, 64), 256, 0, stream>>>(
        gated_bf, V_DIM, wp_t, V_DIM, b_p, out, E_DIM, V_DIM / 32);
}

// Round 8
// 361.211 us; speedup vs baseline: 1.5977x; 1.1994x over previous
//
#include <hip/hip_runtime.h>
#include <math.h>

#define BT      4096
#define T_SEQ   2048
#define E_DIM   1024
#define V_DIM   2048
#define DK      128
#define DV      256
#define QKV_LD  4096

typedef unsigned short ushort_t;
typedef __attribute__((ext_vector_type(8)))  short bf16x8;
typedef __attribute__((ext_vector_type(4)))  unsigned short u16x4;
typedef __attribute__((ext_vector_type(16))) float f32x16;

__device__ __forceinline__ void decay_params(int h, float& ld, float& gamma) {
    const float s0 = -3.4657359027997265f;  // ln(1/32)
    const float e0 = -6.2383246250395092f;  // ln(1/512)
    float lin = s0 + (e0 - s0) * ((float)h * (1.0f / 7.0f));
    gamma = 1.0f - expf(lin);
    ld = logf(gamma);
}

__device__ __forceinline__ short f2bf(float f) {
    unsigned u = __float_as_uint(f);
    unsigned r = (u + 0x7fffu + ((u >> 16) & 1u)) >> 16;
    return (short)r;
}
__device__ __forceinline__ float bf2f(ushort_t u) {
    return __uint_as_float((unsigned)u << 16);
}

__device__ __forceinline__ void async_copy16(void* lds, const void* g) {
    __builtin_amdgcn_global_load_lds(
        (const __attribute__((address_space(1))) unsigned int*)g,
        (__attribute__((address_space(3))) unsigned int*)lds, 16, 0, 0);
}

// ---------------------------------------------------------------------------
// fp32 -> bf16 elementwise
// ---------------------------------------------------------------------------
__global__ __launch_bounds__(256)
void f32_to_bf16_kernel(const float* __restrict__ in, ushort_t* __restrict__ out)
{
    int i = (blockIdx.x * 256 + threadIdx.x) * 8;
    float4 a = *(const float4*)&in[i];
    float4 b = *(const float4*)&in[i + 4];
    bf16x8 o;
    o[0] = f2bf(a.x); o[1] = f2bf(a.y); o[2] = f2bf(a.z); o[3] = f2bf(a.w);
    o[4] = f2bf(b.x); o[5] = f2bf(b.y); o[6] = f2bf(b.z); o[7] = f2bf(b.w);
    *(bf16x8*)&out[i] = o;
}

// ---------------------------------------------------------------------------
// W[K][N] fp32 -> Wt[N][K] bf16
// ---------------------------------------------------------------------------
__global__ __launch_bounds__(256)
void transpose_w_kernel(const float* __restrict__ W, ushort_t* __restrict__ Wt,
                        int K, int N)
{
    __shared__ float tile[32][33];
    const int k0 = blockIdx.y * 32, n0 = blockIdx.x * 32;
    const int t = threadIdx.x;
    const int r = t >> 3, c = (t & 7) * 4;
    float4 v = *(const float4*)&W[(size_t)(k0 + r) * N + n0 + c];
    tile[r][c] = v.x; tile[r][c + 1] = v.y; tile[r][c + 2] = v.z; tile[r][c + 3] = v.w;
    __syncthreads();
    u16x4 o;
    o[0] = (ushort_t)f2bf(tile[c][r]);
    o[1] = (ushort_t)f2bf(tile[c + 1][r]);
    o[2] = (ushort_t)f2bf(tile[c + 2][r]);
    o[3] = (ushort_t)f2bf(tile[c + 3][r]);
    *(u16x4*)&Wt[(size_t)(n0 + r) * K + k0 + c] = o;
}

// ---------------------------------------------------------------------------
// bf16 MFMA GEMM (round-3 verified structure), 128x128 tile, BK=32.
// EPI 0: fp32 out = acc + bias[col]
// EPI 1: bf16 out = silu(acc + bias[col]) * bf2f(extra_bf16[row][col])
// ---------------------------------------------------------------------------
template<int EPI>
__global__ __launch_bounds__(256)
void gemm_bf16(const ushort_t* __restrict__ A, int lda,
               const ushort_t* __restrict__ Bt, int ldb,
               const float* __restrict__ bias,
               void* __restrict__ Cv, int ldc,
               const void* __restrict__ extra, int lde,
               int nkt)
{
    __shared__ ushort_t As[128 * 32];
    __shared__ ushort_t Bs[128 * 32];

    const int tid = threadIdx.x;
    const int w  = tid >> 6, l = tid & 63;
    const int lc = l & 31, q = l >> 5;
    const int wr = w >> 1, wc = w & 1;
    const int m0 = blockIdx.y * 128, n0 = blockIdx.x * 128;

    const int r0 = tid >> 2,         kc0 = (tid & 3) ^ ((r0 >> 1) & 3);
    const int r1 = (256 + tid) >> 2, kc1 = (tid & 3) ^ ((r1 >> 1) & 3);
    const ushort_t* gA0 = A  + (size_t)(m0 + r0) * lda + kc0 * 8;
    const ushort_t* gA1 = A  + (size_t)(m0 + r1) * lda + kc1 * 8;
    const ushort_t* gB0 = Bt + (size_t)(n0 + r0) * ldb + kc0 * 8;
    const ushort_t* gB1 = Bt + (size_t)(n0 + r1) * ldb + kc1 * 8;
    ushort_t* lA0 = &As[(w * 64) * 8];
    ushort_t* lA1 = &As[(256 + w * 64) * 8];
    ushort_t* lB0 = &Bs[(w * 64) * 8];
    ushort_t* lB1 = &Bs[(256 + w * 64) * 8];

    const int sl = (lc >> 1) & 3;
    const bf16x8* apt[2][2];
    const bf16x8* bpt[2][2];
    #pragma unroll
    for (int mi = 0; mi < 2; ++mi)
        #pragma unroll
        for (int ks = 0; ks < 2; ++ks) {
            const int kc = ks * 2 + q;
            const int mrow = wr * 64 + mi * 32 + lc;
            const int nrow = wc * 64 + mi * 32 + lc;
            apt[mi][ks] = (const bf16x8*)&As[(mrow * 4 + (kc ^ sl)) * 8];
            bpt[mi][ks] = (const bf16x8*)&Bs[(nrow * 4 + (kc ^ sl)) * 8];
        }

    f32x16 acc[2][2];
    #pragma unroll
    for (int mi = 0; mi < 2; ++mi)
        #pragma unroll
        for (int ni = 0; ni < 2; ++ni)
            #pragma unroll
            for (int e = 0; e < 16; ++e) acc[mi][ni][e] = 0.0f;

    for (int kt = 0; kt < nkt; ++kt) {
        async_copy16(lA0, gA0); async_copy16(lA1, gA1);
        async_copy16(lB0, gB0); async_copy16(lB1, gB1);
        gA0 += 32; gA1 += 32; gB0 += 32; gB1 += 32;
        __syncthreads();

        bf16x8 a[2][2], b[2][2];
        #pragma unroll
        for (int mi = 0; mi < 2; ++mi)
            #pragma unroll
            for (int ks = 0; ks < 2; ++ks) {
                a[mi][ks] = *apt[mi][ks];
                b[mi][ks] = *bpt[mi][ks];
            }
        #pragma unroll
        for (int ks = 0; ks < 2; ++ks)
            #pragma unroll
            for (int mi = 0; mi < 2; ++mi)
                #pragma unroll
                for (int ni = 0; ni < 2; ++ni)
                    acc[mi][ni] = __builtin_amdgcn_mfma_f32_32x32x16_bf16(
                        a[mi][ks], b[ni][ks], acc[mi][ni], 0, 0, 0);
        __syncthreads();
    }

    #pragma unroll
    for (int ni = 0; ni < 2; ++ni) {
        const int col = n0 + wc * 64 + ni * 32 + lc;
        const float bb = bias[col];
        #pragma unroll
        for (int mi = 0; mi < 2; ++mi) {
            #pragma unroll
            for (int r = 0; r < 16; ++r) {
                const int row = m0 + wr * 64 + mi * 32 + (r & 3) + 8 * (r >> 2) + 4 * q;
                float val = acc[mi][ni][r] + bb;
                if (EPI == 0) {
                    ((float*)Cv)[(size_t)row * ldc + col] = val;
                } else {
                    const float e = bf2f(((const ushort_t*)extra)[(size_t)row * lde + col]);
                    val = val / (1.0f + expf(-val)) * e;
                    ((ushort_t*)Cv)[(size_t)row * ldc + col] = (ushort_t)f2bf(val);
                }
            }
        }
    }
}

// ---------------------------------------------------------------------------
// TM=64 GEMM (proj: 512 blocks, 2/CU). fp32 out + bias[col].
// ---------------------------------------------------------------------------
__global__ __launch_bounds__(256)
void gemm_tm64(const ushort_t* __restrict__ A, int lda,
               const ushort_t* __restrict__ Bt, int ldb,
               const float* __restrict__ bias,
               float* __restrict__ C, int ldc, int nkt)
{
    __shared__ ushort_t As[64 * 32];
    __shared__ ushort_t Bs[128 * 32];

    const int tid = threadIdx.x;
    const int w  = tid >> 6, l = tid & 63;
    const int lc = l & 31, q = l >> 5;
    const int wr = w >> 1, wc = w & 1;
    const int m0 = blockIdx.y * 64, n0 = blockIdx.x * 128;

    const int rA = tid >> 2,          kcA = (tid & 3) ^ ((rA >> 1) & 3);
    const int rB1 = (256 + tid) >> 2, kcB1 = (tid & 3) ^ ((rB1 >> 1) & 3);
    const ushort_t* gA  = A  + (size_t)(m0 + rA)  * lda + kcA  * 8;
    const ushort_t* gB0 = Bt + (size_t)(n0 + rA)  * ldb + kcA  * 8;
    const ushort_t* gB1 = Bt + (size_t)(n0 + rB1) * ldb + kcB1 * 8;
    ushort_t* lA  = &As[(w * 64) * 8];
    ushort_t* lB0 = &Bs[(w * 64) * 8];
    ushort_t* lB1 = &Bs[(256 + w * 64) * 8];

    const int sl = (lc >> 1) & 3;
    const bf16x8* apt[2];
    const bf16x8* bpt[2][2];
    #pragma unroll
    for (int ks = 0; ks < 2; ++ks) {
        const int kc = ks * 2 + q;
        const int mrow = wr * 32 + lc;
        apt[ks] = (const bf16x8*)&As[(mrow * 4 + (kc ^ sl)) * 8];
        #pragma unroll
        for (int ni = 0; ni < 2; ++ni) {
            const int nrow = wc * 64 + ni * 32 + lc;
            bpt[ni][ks] = (const bf16x8*)&Bs[(nrow * 4 + (kc ^ sl)) * 8];
        }
    }

    f32x16 acc[2];
    #pragma unroll
    for (int ni = 0; ni < 2; ++ni)
        #pragma unroll
        for (int e = 0; e < 16; ++e) acc[ni][e] = 0.0f;

    for (int kt = 0; kt < nkt; ++kt) {
        async_copy16(lA, gA);
        async_copy16(lB0, gB0); async_copy16(lB1, gB1);
        gA += 32; gB0 += 32; gB1 += 32;
        __syncthreads();
        bf16x8 a[2], b[2][2];
        #pragma unroll
        for (int ks = 0; ks < 2; ++ks) {
            a[ks] = *apt[ks];
            b[0][ks] = *bpt[0][ks];
            b[1][ks] = *bpt[1][ks];
        }
        #pragma unroll
        for (int ks = 0; ks < 2; ++ks)
            #pragma unroll
            for (int ni = 0; ni < 2; ++ni)
                acc[ni] = __builtin_amdgcn_mfma_f32_32x32x16_bf16(
                    a[ks], b[ni][ks], acc[ni], 0, 0, 0);
        __syncthreads();
    }

    #pragma unroll
    for (int ni = 0; ni < 2; ++ni) {
        const int col = n0 + wc * 64 + ni * 32 + lc;
        const float bb = bias[col];
        #pragma unroll
        for (int r = 0; r < 16; ++r) {
            const int row = m0 + wr * 32 + (r & 3) + 8 * (r >> 2) + 4 * q;
            C[(size_t)row * ldc + col] = acc[ni][r] + bb;
        }
    }
}

// ---------------------------------------------------------------------------
// q/k prep: xpos + gamma^{+-(t&63)} pre-scale, bf16 head-major [bh][T][128]
// ---------------------------------------------------------------------------
__global__ __launch_bounds__(256)
void qk_prep(const float* __restrict__ qkv,
             ushort_t* __restrict__ qh, ushort_t* __restrict__ kh)
{
    const int row = blockIdx.x;
    const int t = threadIdx.x;
    const int b = row >> 11, trow = row & (T_SEQ - 1);
    const bool isK = t >= 128;
    const int col0 = (t & 127) * 8;
    const int h = col0 >> 7, d = col0 & 127;

    float ld, gamma;
    decay_params(h, ld, gamma);
    const float gsc = expf(isK ? -ld * (float)(trow & 63) : ld * (float)(trow & 63));

    const float* src = qkv + (size_t)row * QKV_LD + (isK ? E_DIM : 0) + col0;
    float4 x0 = *(const float4*)src;
    float4 x1 = *(const float4*)(src + 4);
    float xv[8] = {x0.x, x0.y, x0.z, x0.w, x1.x, x1.y, x1.z, x1.w};

    bf16x8 o;
    #pragma unroll
    for (int pi = 0; pi < 4; ++pi) {
        const int ip = col0 / 2 + pi;
        float sv = (2.0f * (float)ip + 409.6f) * (1.0f / 1433.6f);
        float sc = powf(sv, (float)trow * (1.0f / 512.0f));
        if (isK) sc = 1.0f / sc;
        float invf = powf(10000.0f, -(float)ip * (1.0f / 512.0f));
        float sn, cs;
        sincosf((float)trow * invf, &sn, &cs);
        float c = cs * sc * gsc, s = sn * sc * gsc;
        float a = xv[2 * pi], bb = xv[2 * pi + 1];
        o[2 * pi]     = f2bf(a * c - bb * s);
        o[2 * pi + 1] = f2bf(bb * c + a * s);
    }
    ushort_t* dst = (isK ? kh : qh) + ((size_t)(b * 8 + h) * T_SEQ + trow) * 128 + d;
    *(bf16x8*)dst = o;
}

// ---------------------------------------------------------------------------
// V transpose: fp32 v-section -> vt [bh][256][T] bf16
// ---------------------------------------------------------------------------
__global__ __launch_bounds__(256)
void v_transpose(const float* __restrict__ qkv, ushort_t* __restrict__ vt)
{
    __shared__ float tile[32][33];
    const int j0 = blockIdx.x * 32;
    const int zz = blockIdx.y;
    const int bh = zz >> 3, v0 = (zz & 7) * 32;
    const int b = bh >> 3, h = bh & 7;
    const int t = threadIdx.x;
    const int r = t >> 3, c = (t & 7) * 4;

    float4 x = *(const float4*)(qkv + (size_t)(b * T_SEQ + j0 + r) * QKV_LD
                                + 2 * E_DIM + h * DV + v0 + c);
    tile[r][c] = x.x; tile[r][c+1] = x.y; tile[r][c+2] = x.z; tile[r][c+3] = x.w;
    __syncthreads();
    u16x4 o;
    o[0] = (ushort_t)f2bf(tile[c][r]);
    o[1] = (ushort_t)f2bf(tile[c + 1][r]);
    o[2] = (ushort_t)f2bf(tile[c + 2][r]);
    o[3] = (ushort_t)f2bf(tile[c + 3][r]);
    *(u16x4*)&vt[((size_t)bh * 256 + v0 + r) * T_SEQ + j0 + c] = o;
}

// ---------------------------------------------------------------------------
// kt2 = gamma^63 * kh^T per head: [bh][T][128] -> [bh][128][T]
// ---------------------------------------------------------------------------
__global__ __launch_bounds__(256)
void kt2_kernel(const ushort_t* __restrict__ kh, ushort_t* __restrict__ kt2)
{
    __shared__ ushort_t tile[32][40];
    const int j0 = blockIdx.x * 32;
    const int zz = blockIdx.y;
    const int bh = zz >> 2, k0 = (zz & 3) * 32;
    const int t = threadIdx.x;
    const int r = t >> 3, c = (t & 7) * 4;
    float ld, gamma; decay_params(bh & 7, ld, gamma);
    const float g63 = expf(ld * 63.0f);
    *(u16x4*)&tile[r][c] = *(const u16x4*)&kh[((size_t)bh * T_SEQ + j0 + r) * 128 + k0 + c];
    __syncthreads();
    u16x4 o;
    o[0] = (ushort_t)f2bf(bf2f(tile[c][r])     * g63);
    o[1] = (ushort_t)f2bf(bf2f(tile[c + 1][r]) * g63);
    o[2] = (ushort_t)f2bf(bf2f(tile[c + 2][r]) * g63);
    o[3] = (ushort_t)f2bf(bf2f(tile[c + 3][r]) * g63);
    *(u16x4*)&kt2[((size_t)bh * 128 + k0 + r) * T_SEQ + j0 + c] = o;
}

// ---------------------------------------------------------------------------
// Phase A: A_c[v][k] = sum_{j in chunk} vt[v][j] * kt2[k][j]  (bf16)
// ---------------------------------------------------------------------------
__global__ __launch_bounds__(256)
void chunk_kv(const ushort_t* __restrict__ vt, const ushort_t* __restrict__ kt2,
              ushort_t* __restrict__ Abuf)
{
    const int c = blockIdx.x;
    const int bh = blockIdx.y;
    const int tid = threadIdx.x;
    const int w = tid >> 6, l = tid & 63, lc = l & 31, q = l >> 5;
    const int j0 = c * 64;

    f32x16 acc[2][4];
    #pragma unroll
    for (int mi = 0; mi < 2; ++mi)
        #pragma unroll
        for (int ni = 0; ni < 4; ++ni)
            #pragma unroll
            for (int e = 0; e < 16; ++e) acc[mi][ni][e] = 0.0f;

    #pragma unroll
    for (int ks = 0; ks < 4; ++ks) {
        bf16x8 a[2], bfr[4];
        #pragma unroll
        for (int mi = 0; mi < 2; ++mi)
            a[mi] = *(const bf16x8*)(vt + ((size_t)bh * 256 + w * 64 + mi * 32 + lc) * T_SEQ
                                     + j0 + ks * 16 + q * 8);
        #pragma unroll
        for (int ni = 0; ni < 4; ++ni)
            bfr[ni] = *(const bf16x8*)(kt2 + ((size_t)bh * 128 + ni * 32 + lc) * T_SEQ
                                       + j0 + ks * 16 + q * 8);
        #pragma unroll
        for (int mi = 0; mi < 2; ++mi)
            #pragma unroll
            for (int ni = 0; ni < 4; ++ni)
                acc[mi][ni] = __builtin_amdgcn_mfma_f32_32x32x16_bf16(
                    a[mi], bfr[ni], acc[mi][ni], 0, 0, 0);
    }

    ushort_t* ab = Abuf + (size_t)(bh * 32 + c) * 256 * 128;
    #pragma unroll
    for (int mi = 0; mi < 2; ++mi)
        #pragma unroll
        for (int ni = 0; ni < 4; ++ni)
            #pragma unroll
            for (int r = 0; r < 16; ++r) {
                const int v = w * 64 + mi * 32 + (r & 3) + 8 * (r >> 2) + 4 * q;
                const int k = ni * 32 + lc;
                ab[(size_t)v * 128 + k] = (ushort_t)f2bf(acc[mi][ni][r]);
            }
}

// ---------------------------------------------------------------------------
// Phase B: scan over chunks. St[c] = gamma * S_c (bf16), S_{c+1} = g64*S_c + A_c.
// Final state -> curr_kv (fp32).
// ---------------------------------------------------------------------------
__global__ __launch_bounds__(256)
void scan_state(const ushort_t* __restrict__ Abuf, ushort_t* __restrict__ St,
                float* __restrict__ ckv)
{
    const int blk = blockIdx.x;
    const int bh = blk >> 7, sub = blk & 127;
    const int tid = threadIdx.x;
    const int v = sub * 2 + (tid >> 7), k = tid & 127;

    float ld, gamma;
    decay_params(bh & 7, ld, gamma);
    const float g64 = expf(ld * 64.0f);

    const size_t base = ((size_t)bh * 32 * 256 + v) * 128 + k;
    const size_t cstr = 256 * 128;
    float s = 0.0f;
    for (int c = 0; c < 32; ++c) {
        const size_t off = base + (size_t)c * cstr;
        St[off] = (ushort_t)f2bf(gamma * s);
        s = g64 * s + bf2f(Abuf[off]);
    }
    const float inv_scale = rsqrtf((1.0f - expf(ld * (float)T_SEQ)) / (1.0f - gamma));
    ckv[((size_t)bh * 128 + k) * 256 + v] = s * inv_scale;
}

// ---------------------------------------------------------------------------
// Phase C: per-i-tile output, single-wave blocks, fused groupnorm -> bf16.
// ---------------------------------------------------------------------------
__global__ __launch_bounds__(64)
void retention_chunk(const ushort_t* __restrict__ qh,
                     const ushort_t* __restrict__ kh,
                     const ushort_t* __restrict__ vt,
                     const ushort_t* __restrict__ St,
                     ushort_t* __restrict__ normed)
{
    const int it = blockIdx.x;
    const int bh = blockIdx.y;
    const int b = bh >> 3, h = bh & 7;
    const int c = it >> 1, w = it & 1;
    const int l = threadIdx.x, lc = l & 31, q = l >> 5;
    const int i0 = it * 32;
    const size_t bhT = (size_t)bh * T_SEQ;

    float ld, gamma;
    decay_params(h, ld, gamma);

    bf16x8 qf[8];
    {
        const ushort_t* qp = qh + (bhT + i0 + lc) * 128 + q * 8;
        #pragma unroll
        for (int c8 = 0; c8 < 8; ++c8)
            qf[c8] = *(const bf16x8*)(qp + c8 * 16);
    }

    f32x16 acc[8];
    #pragma unroll
    for (int vg = 0; vg < 8; ++vg)
        #pragma unroll
        for (int e = 0; e < 16; ++e) acc[vg][e] = 0.0f;

    if (c > 0) {
        const ushort_t* sp = St + ((size_t)(bh * 32 + c) * 256 + lc) * 128 + q * 8;
        #pragma unroll
        for (int vg = 0; vg < 8; ++vg) {
            const ushort_t* spv = sp + (size_t)vg * 32 * 128;
            #pragma unroll
            for (int ks = 0; ks < 8; ++ks) {
                bf16x8 sb = *(const bf16x8*)(spv + ks * 16);
                acc[vg] = __builtin_amdgcn_mfma_f32_32x32x16_bf16(
                    qf[ks], sb, acc[vg], 0, 0, 0);
            }
        }
    }

    for (int jt2 = 0; jt2 <= w; ++jt2) {
        const int j0 = c * 64 + jt2 * 32;

        f32x16 s;
        #pragma unroll
        for (int e = 0; e < 16; ++e) s[e] = 0.0f;
        const ushort_t* kp = kh + (bhT + j0 + lc) * 128 + q * 8;
        #pragma unroll
        for (int c8 = 0; c8 < 8; ++c8) {
            bf16x8 ka = *(const bf16x8*)(kp + c8 * 16);
            s = __builtin_amdgcn_mfma_f32_32x32x16_bf16(ka, qf[c8], s, 0, 0, 0);
        }

        float sv[16];
        #pragma unroll
        for (int r = 0; r < 16; ++r) {
            float val = s[r];
            if (jt2 == w) {
                int jr_ = (r & 3) + 8 * (r >> 2) + 4 * q;
                val = (jr_ <= lc) ? val : 0.0f;
            }
            sv[r] = val;
        }

        bf16x8 pa0, pa1;
        #pragma unroll
        for (int e = 0; e < 4; ++e) {
            float t1 = __shfl_xor(sv[e + 4], 32);
            float t0 = __shfl_xor(sv[e], 32);
            pa0[e]     = f2bf(q ? t1 : sv[e]);
            pa0[e + 4] = f2bf(q ? sv[e + 4] : t0);
            float t3 = __shfl_xor(sv[e + 12], 32);
            float t2 = __shfl_xor(sv[e + 8], 32);
            pa1[e]     = f2bf(q ? t3 : sv[e + 8]);
            pa1[e + 4] = f2bf(q ? sv[e + 12] : t2);
        }

        #pragma unroll
        for (int vg = 0; vg < 8; ++vg) {
            const ushort_t* vp = vt + ((size_t)bh * 256 + vg * 32 + lc) * T_SEQ + j0 + q * 8;
            bf16x8 vb0 = *(const bf16x8*)vp;
            bf16x8 vb1 = *(const bf16x8*)(vp + 16);
            acc[vg] = __builtin_amdgcn_mfma_f32_32x32x16_bf16(pa0, vb0, acc[vg], 0, 0, 0);
            acc[vg] = __builtin_amdgcn_mfma_f32_32x32x16_bf16(pa1, vb1, acc[vg], 0, 0, 0);
        }
    }

    #pragma unroll
    for (int r = 0; r < 16; ++r) {
        const int il = (r & 3) + 8 * (r >> 2) + 4 * q;
        const int i  = i0 + il;
        float denom = (1.0f - expf(ld * (float)(i + 1))) / (1.0f - gamma);
        float fs = 0.08838834764831845f * rsqrtf(denom);
        float vals[8];
        float a1 = 0.0f, a2 = 0.0f;
        #pragma unroll
        for (int vg = 0; vg < 8; ++vg) {
            float x = acc[vg][r] * fs;
            vals[vg] = x;
            a1 += x; a2 += x * x;
        }
        a1 += __shfl_xor(a1, 1);  a2 += __shfl_xor(a2, 1);
        a1 += __shfl_xor(a1, 2);  a2 += __shfl_xor(a2, 2);
        a1 += __shfl_xor(a1, 4);  a2 += __shfl_xor(a2, 4);
        a1 += __shfl_xor(a1, 8);  a2 += __shfl_xor(a2, 8);
        a1 += __shfl_xor(a1, 16); a2 += __shfl_xor(a2, 16);
        float mu = a1 * (1.0f / 256.0f);
        float var = a2 * (1.0f / 256.0f) - mu * mu;
        float rs = rsqrtf(var + 1e-5f);
        ushort_t* op = normed + ((size_t)(b * T_SEQ + i)) * V_DIM + h * DV + lc;
        #pragma unroll
        for (int vg = 0; vg < 8; ++vg)
            op[vg * 32] = (ushort_t)f2bf((vals[vg] - mu) * rs);
    }
}

// ---------------------------------------------------------------------------
extern "C" void kernel_launch(void* const* d_in, const int* in_sizes, int n_in,
                              void* d_out, int out_size, void* d_ws, size_t ws_size,
                              hipStream_t stream)
{
    const float* hs    = (const float*)d_in[0];
    const float* w_qkv = (const float*)d_in[1];
    const float* b_qkv = (const float*)d_in[2];
    const float* w_g   = (const float*)d_in[3];
    const float* b_g   = (const float*)d_in[4];
    const float* w_p   = (const float*)d_in[5];
    const float* b_p   = (const float*)d_in[6];
    float* out = (float*)d_out;

    const size_t MB = 1024 * 1024;
    // ws (96MB) timeline (round-5 proven choreography):
    //   [0,64)  fp32 qkv (gemm->preps) -> Abuf [0,32) (A->scan) -> normed bf16 [0,16) (C->gated)
    //   [32,64) St (scan->C) -> gated_bf[32,48) + hs_bf2[48,56) + wg_t[56,60) + wp_t[60,64)
    //   [64,72) qh   [72,88) vt   [88,96) wqkv_t
    float*    qkv      = (float*)d_ws;
    ushort_t* Abuf     = (ushort_t*)d_ws;
    ushort_t* normed   = (ushort_t*)d_ws;
    ushort_t* Stbuf    = (ushort_t*)((char*)d_ws + 32 * MB);
    ushort_t* gated_bf = (ushort_t*)((char*)d_ws + 32 * MB);
    ushort_t* hs_bf2   = (ushort_t*)((char*)d_ws + 48 * MB);
    ushort_t* wg_t     = (ushort_t*)((char*)d_ws + 56 * MB);
    ushort_t* wp_t     = (ushort_t*)((char*)d_ws + 60 * MB);
    ushort_t* qh       = (ushort_t*)((char*)d_ws + 64 * MB);
    ushort_t* vt       = (ushort_t*)((char*)d_ws + 72 * MB);
    ushort_t* wqkv_t   = (ushort_t*)((char*)d_ws + 88 * MB);
    // d_out scratch: hs_bf1 / kh at [0,8), kt2 at [8,16) — dead before proj store.
    ushort_t* hs_bf1   = (ushort_t*)d_out;
    ushort_t* kh       = (ushort_t*)d_out;
    ushort_t* kt2      = (ushort_t*)((char*)d_out + 8 * MB);
    float*    ckv_out  = out + (size_t)BT * E_DIM;

    // 1. conversions for qkv GEMM
    f32_to_bf16_kernel<<<dim3(2048), 256, 0, stream>>>(hs, hs_bf1);
    transpose_w_kernel<<<dim3(128, 32), 256, 0, stream>>>(w_qkv, wqkv_t, E_DIM, 4096);

    // 2. qkv = hs @ w_qkv + b_qkv (fp32)
    gemm_bf16<0><<<dim3(32, 32), 256, 0, stream>>>(
        hs_bf1, E_DIM, wqkv_t, E_DIM, b_qkv, qkv, QKV_LD, nullptr, 0, E_DIM / 32);

    // 3. preps (consume fp32 qkv); kh overwrites hs_bf1 (dead after GEMM)
    qk_prep<<<dim3(BT), 256, 0, stream>>>(qkv, qh, kh);
    v_transpose<<<dim3(64, 128), 256, 0, stream>>>(qkv, vt);
    kt2_kernel<<<dim3(64, 64), 256, 0, stream>>>(kh, kt2);

    // 4. chunked retention: A -> scan(S, curr_kv) -> outputs+groupnorm (bf16)
    chunk_kv<<<dim3(32, 16), 256, 0, stream>>>(vt, kt2, Abuf);
    scan_state<<<dim3(2048), 256, 0, stream>>>(Abuf, Stbuf, ckv_out);
    retention_chunk<<<dim3(64, 16), 64, 0, stream>>>(qh, kh, vt, Stbuf, normed);

    // 5. late conversions (St/A regions free now)
    f32_to_bf16_kernel<<<dim3(2048), 256, 0, stream>>>(hs, hs_bf2);
    transpose_w_kernel<<<dim3(64, 32), 256, 0, stream>>>(w_g, wg_t, E_DIM, V_DIM);
    transpose_w_kernel<<<dim3(32, 64), 256, 0, stream>>>(w_p, wp_t, V_DIM, E_DIM);

    // 6. gated = silu(hs @ w_g + b_g) * normed(bf16) -> bf16
    gemm_bf16<1><<<dim3(16, 32), 256, 0, stream>>>(
        hs_bf2, E_DIM, wg_t, E_DIM, b_g, gated_bf, V_DIM, normed, V_DIM, E_DIM / 32);

    // 7. proj = gated @ w_p + b_p (TM=64 -> 512 blocks; overwrites kh/kt2)
    gemm_tm64<<<dim3(8, 64), 256, 0, stream>>>(
        gated_bf, V_DIM, wp_t, V_DIM, b_p, out, E_DIM, V_DIM / 32);
}